// Round 1
// baseline (792.737 us; speedup 1.0000x reference)
//
#include <hip/hip_runtime.h>
#include <hip/hip_cooperative_groups.h>
#include <stdint.h>

namespace cg = cooperative_groups;

#define NBINS 256
#define HW_SHIFT 20            // h*w = 1024*1024 = 1<<20 floats per image
#define HW4_SHIFT 18           // float4 per image = 1<<18
#define GRID 768               // 3 blocks/CU (LDS 32KB -> 5/CU cap, safe co-residency)
#define BLOCK 256
#define NCOPY 32               // replicated LDS histograms, one per bank
#define CHUNKS_PER_IMG 32      // 48*32 = 1536 chunks = exactly 2 rounds over 768 blocks
#define CHUNK4 8192            // float4 per chunk

typedef float nfloat4 __attribute__((ext_vector_type(4))); // clang vector: NT-store OK

__device__ __forceinline__ unsigned enc_f(float f) {
    unsigned u = __float_as_uint(f);
    return u ^ ((unsigned)((int)u >> 31) | 0x80000000u); // order-preserving monotone map
}

// ws layout (every slot written unconditionally every run -> no init needed):
//   [0 .. 2*GRID)                       per-block {mn,mx} float pairs
//   [.. + nimg*32*NBINS)                partial histograms (unsigned)
//   [.. + nimg)                         thresholds (float)

__global__ void __launch_bounds__(BLOCK, 3)
k_fused_otsu(const float4* __restrict__ x, nfloat4* __restrict__ out,
             float* __restrict__ ws, int nimg) {
    cg::grid_group grid = cg::this_grid();
    __shared__ unsigned sh[NBINS * NCOPY];  // 32 KB, reused across all phases

    const int tid = threadIdx.x;
    const int bid = blockIdx.x;
    const int lane = tid & 63;
    const int wv = tid >> 6;
    const long n4 = (long)nimg << HW4_SHIFT;
    const long stride = (long)GRID * BLOCK;

    float2* bmm = (float2*)ws;                                   // GRID pairs
    unsigned* partial = (unsigned*)(ws + 2 * GRID);              // nimg*32*NBINS
    float* thresh = ws + 2 * GRID + (long)nimg * CHUNKS_PER_IMG * NBINS;

    // ---------------- Phase 1: global min/max (HBM pass, 4-deep MLP) ----------------
    float mn = __builtin_inff(), mx = -__builtin_inff();
    {
        long i = (long)bid * BLOCK + tid;
        for (; i + 3 * stride < n4; i += 4 * stride) {
            float4 a = x[i];
            float4 b = x[i + stride];
            float4 c4 = x[i + 2 * stride];
            float4 d = x[i + 3 * stride];
            mn = fminf(mn, fminf(fminf(a.x, a.y), fminf(a.z, a.w)));
            mx = fmaxf(mx, fmaxf(fmaxf(a.x, a.y), fmaxf(a.z, a.w)));
            mn = fminf(mn, fminf(fminf(b.x, b.y), fminf(b.z, b.w)));
            mx = fmaxf(mx, fmaxf(fmaxf(b.x, b.y), fmaxf(b.z, b.w)));
            mn = fminf(mn, fminf(fminf(c4.x, c4.y), fminf(c4.z, c4.w)));
            mx = fmaxf(mx, fmaxf(fmaxf(c4.x, c4.y), fmaxf(c4.z, c4.w)));
            mn = fminf(mn, fminf(fminf(d.x, d.y), fminf(d.z, d.w)));
            mx = fmaxf(mx, fmaxf(fmaxf(d.x, d.y), fmaxf(d.z, d.w)));
        }
        for (; i < n4; i += stride) {
            float4 a = x[i];
            mn = fminf(mn, fminf(fminf(a.x, a.y), fminf(a.z, a.w)));
            mx = fmaxf(mx, fmaxf(fmaxf(a.x, a.y), fmaxf(a.z, a.w)));
        }
    }
    for (int off = 32; off; off >>= 1) {
        mn = fminf(mn, __shfl_down(mn, off));
        mx = fmaxf(mx, __shfl_down(mx, off));
    }
    if (lane == 0) { sh[2 * wv] = __float_as_uint(mn); sh[2 * wv + 1] = __float_as_uint(mx); }
    __syncthreads();
    if (tid == 0) {
        for (int j = 1; j < BLOCK / 64; j++) {
            mn = fminf(mn, __uint_as_float(sh[2 * j]));
            mx = fmaxf(mx, __uint_as_float(sh[2 * j + 1]));
        }
        bmm[bid] = make_float2(mn, mx);
    }
    __threadfence();
    grid.sync();

    // ---------------- Phase 1b: every block reduces all 768 pairs (no single-block kernel) ----
    mn = __builtin_inff(); mx = -__builtin_inff();
    for (int j = tid; j < GRID; j += BLOCK) {
        float2 v = bmm[j];
        mn = fminf(mn, v.x); mx = fmaxf(mx, v.y);
    }
    for (int off = 32; off; off >>= 1) {
        mn = fminf(mn, __shfl_down(mn, off));
        mx = fmaxf(mx, __shfl_down(mx, off));
    }
    if (lane == 0) { sh[2 * wv] = __float_as_uint(mn); sh[2 * wv + 1] = __float_as_uint(mx); }
    __syncthreads();
    if (tid == 0) {
        for (int j = 1; j < BLOCK / 64; j++) {
            mn = fminf(mn, __uint_as_float(sh[2 * j]));
            mx = fmaxf(mx, __uint_as_float(sh[2 * j + 1]));
        }
        sh[0] = __float_as_uint(mn); sh[1] = __float_as_uint(mx);
    }
    __syncthreads();
    mn = __uint_as_float(sh[0]);
    mx = __uint_as_float(sh[1]);
    float span = mx - mn;                    // fp32 sub, matches np
    float scale = __fdiv_rn(256.0f, span);   // NBINS/span in fp32

    // ---------------- Phase 2: per-chunk histograms (L3-resident pass) ----------------
    const int nchunks = nimg * CHUNKS_PER_IMG;
    const int c = tid & (NCOPY - 1);
    for (int chunk = bid; chunk < nchunks; chunk += GRID) {
        __syncthreads();                                   // sh reuse guard
        for (int i = tid; i < NBINS * NCOPY; i += BLOCK) sh[i] = 0u;
        __syncthreads();
        const float4* base = x + ((long)(chunk >> 5) << HW4_SHIFT)
                               + (long)(chunk & (CHUNKS_PER_IMG - 1)) * CHUNK4;
        for (int i = tid; i < CHUNK4; i += 2 * BLOCK) {
            float4 v0 = base[i];
            float4 v1 = base[i + BLOCK];
            // (x - mn) * scale : sub then mul, not an FMA shape -> no contraction
            int b0 = (int)floorf((v0.x - mn) * scale);
            int b1 = (int)floorf((v0.y - mn) * scale);
            int b2 = (int)floorf((v0.z - mn) * scale);
            int b3 = (int)floorf((v0.w - mn) * scale);
            int b4 = (int)floorf((v1.x - mn) * scale);
            int b5 = (int)floorf((v1.y - mn) * scale);
            int b6 = (int)floorf((v1.z - mn) * scale);
            int b7 = (int)floorf((v1.w - mn) * scale);
            b0 = min(max(b0, 0), NBINS - 1); b1 = min(max(b1, 0), NBINS - 1);
            b2 = min(max(b2, 0), NBINS - 1); b3 = min(max(b3, 0), NBINS - 1);
            b4 = min(max(b4, 0), NBINS - 1); b5 = min(max(b5, 0), NBINS - 1);
            b6 = min(max(b6, 0), NBINS - 1); b7 = min(max(b7, 0), NBINS - 1);
            atomicAdd(&sh[b0 * NCOPY + c], 1u);
            atomicAdd(&sh[b1 * NCOPY + c], 1u);
            atomicAdd(&sh[b2 * NCOPY + c], 1u);
            atomicAdd(&sh[b3 * NCOPY + c], 1u);
            atomicAdd(&sh[b4 * NCOPY + c], 1u);
            atomicAdd(&sh[b5 * NCOPY + c], 1u);
            atomicAdd(&sh[b6 * NCOPY + c], 1u);
            atomicAdd(&sh[b7 * NCOPY + c], 1u);
        }
        __syncthreads();
        // blockDim == NBINS: thread t owns bin t; staggered copy index avoids conflicts
        unsigned sum = 0;
        #pragma unroll
        for (int k = 0; k < NCOPY; k++) {
            int cc = (k + tid) & (NCOPY - 1);
            sum += sh[tid * NCOPY + cc];
        }
        partial[(long)chunk * NBINS + tid] = sum;
    }
    __threadfence();
    grid.sync();

    // ---------------- Phase 3: Otsu per image (blocks 0..nimg-1) ----------------
    if (bid < nimg) {
        const unsigned* p = partial + (long)bid * CHUNKS_PER_IMG * NBINS;
        unsigned hsum = 0;
        #pragma unroll 4
        for (int k = 0; k < CHUNKS_PER_IMG; k++) hsum += p[k * NBINS + tid];
        sh[tid] = hsum;
        __syncthreads();
        // sequential fp32 cumsum on thread 0 -> bit-exact np.cumsum order; values to LDS
        if (tid == 0) {
            const float inv_total = 1.0f / 1048576.0f; // exact 2^-20
            float ww = 0.0f, ss = 0.0f;
            for (int t = 0; t < NBINS; t++) {
                float pp = __fmul_rn((float)sh[t], inv_total);
                ww = __fadd_rn(ww, pp);
                ss = __fadd_rn(ss, __fmul_rn(pp, (float)t));
                sh[NBINS + t] = __float_as_uint(ww);
                sh[2 * NBINS + t] = __float_as_uint(ss);
            }
        }
        __syncthreads();
        // variance + argmax fully parallel (divisions off the serial path)
        float total = __uint_as_float(sh[3 * NBINS - 1]);
        float ww = __uint_as_float(sh[NBINS + tid]);
        float ss = __uint_as_float(sh[2 * NBINS + tid]);
        float wf = __fsub_rn(1.0f, ww);
        float var;
        if (ww > 0.0f && wf > 0.0f) {
            float mb = __fdiv_rn(ss, ww);
            float mf = __fdiv_rn(__fsub_rn(total, ss), wf);
            float d = __fsub_rn(mb, mf);
            var = __fmul_rn(__fmul_rn(ww, wf), __fmul_rn(d, d));
        } else {
            var = -__builtin_inff();
        }
        // first-max argmax: key = (enc(var) << 32) | (255 - t); max-reduce
        unsigned long long key = ((unsigned long long)enc_f(var) << 32)
                               | (unsigned)(NBINS - 1 - tid);
        for (int off = 32; off; off >>= 1) {
            unsigned long long o = __shfl_down(key, off);
            key = key > o ? key : o;
        }
        if (lane == 0) {
            sh[3 * NBINS + 2 * wv] = (unsigned)(key & 0xFFFFFFFFull);
            sh[3 * NBINS + 2 * wv + 1] = (unsigned)(key >> 32);
        }
        __syncthreads();
        if (tid == 0) {
            for (int j = 1; j < BLOCK / 64; j++) {
                unsigned long long o = ((unsigned long long)sh[3 * NBINS + 2 * j + 1] << 32)
                                     | sh[3 * NBINS + 2 * j];
                key = key > o ? key : o;
            }
            int bestt = NBINS - 1 - (int)(key & 0xFFFFFFFFull);
            float sp = __fsub_rn(mx, mn);
            float q = __fmul_rn((float)(bestt + 1), 1.0f / 256.0f); // exact (pow2)
            thresh[bid] = __fadd_rn(mn, __fmul_rn(sp, q));          // mul then add, no fma
        }
    }
    __threadfence();
    grid.sync();

    // ---------------- Phase 4: apply (L3 read + NT write, 2-deep MLP) ----------------
    if (tid < nimg) sh[tid] = __float_as_uint(thresh[tid]); // stage thresholds in LDS
    __syncthreads();
    {
        long i = (long)bid * BLOCK + tid;
        for (; i + stride < n4; i += 2 * stride) {
            float4 v0 = x[i];
            float4 v1 = x[i + stride];
            float t0 = __uint_as_float(sh[(int)(i >> HW4_SHIFT)]);
            float t1 = __uint_as_float(sh[(int)((i + stride) >> HW4_SHIFT)]);
            nfloat4 o0, o1;
            o0.x = (v0.x <= t0) ? 0.0f : v0.x;
            o0.y = (v0.y <= t0) ? 0.0f : v0.y;
            o0.z = (v0.z <= t0) ? 0.0f : v0.z;
            o0.w = (v0.w <= t0) ? 0.0f : v0.w;
            o1.x = (v1.x <= t1) ? 0.0f : v1.x;
            o1.y = (v1.y <= t1) ? 0.0f : v1.y;
            o1.z = (v1.z <= t1) ? 0.0f : v1.z;
            o1.w = (v1.w <= t1) ? 0.0f : v1.w;
            __builtin_nontemporal_store(o0, &out[i]);
            __builtin_nontemporal_store(o1, &out[i + stride]);
        }
        for (; i < n4; i += stride) {
            float4 v0 = x[i];
            float t0 = __uint_as_float(sh[(int)(i >> HW4_SHIFT)]);
            nfloat4 o0;
            o0.x = (v0.x <= t0) ? 0.0f : v0.x;
            o0.y = (v0.y <= t0) ? 0.0f : v0.y;
            o0.z = (v0.z <= t0) ? 0.0f : v0.z;
            o0.w = (v0.w <= t0) ? 0.0f : v0.w;
            __builtin_nontemporal_store(o0, &out[i]);
        }
    }
}

extern "C" void kernel_launch(void* const* d_in, const int* in_sizes, int n_in,
                              void* d_out, int out_size, void* d_ws, size_t ws_size,
                              hipStream_t stream) {
    const float4* x = (const float4*)d_in[0];
    nfloat4* out = (nfloat4*)d_out;
    long n = (long)in_sizes[0];          // 48 * 2^20 floats
    int nimg = (int)(n >> HW_SHIFT);     // 48
    float* ws = (float*)d_ws;

    void* args[] = { (void*)&x, (void*)&out, (void*)&ws, (void*)&nimg };
    hipLaunchCooperativeKernel((const void*)k_fused_otsu, dim3(GRID), dim3(BLOCK),
                               args, 0, stream);
}

// Round 2
// 407.929 us; speedup vs baseline: 1.9433x; 1.9433x over previous
//
#include <hip/hip_runtime.h>
#include <stdint.h>

#define NBINS 256
#define HW_SHIFT 20            // h*w = 1024*1024 = 1<<20 floats per image
#define HW4_SHIFT 18           // float4 per image = 1<<18
#define BLOCK 256
#define NCOPY 32               // replicated LDS histograms, one per bank
#define MM_BLOCKS 2048         // minmax blocks (8/CU, 32 waves)
#define HIST_BLOCKS 768        // 3/CU co-resident (32KB LDS), 2 chunks each — balanced
#define CHUNKS_PER_IMG 32      // 48*32 = 1536 chunks
#define CHUNK4 8192            // float4 per chunk
#define APPLY_BLOCKS 2048      // 8/CU, 32 waves

typedef float nfloat4 __attribute__((ext_vector_type(4))); // clang vector: NT-store OK

__device__ __forceinline__ unsigned enc_f(float f) {
    unsigned u = __float_as_uint(f);
    return u ^ ((unsigned)((int)u >> 31) | 0x80000000u); // order-preserving monotone map
}

// ws layout (every slot written unconditionally every run -> no init kernel needed):
//   [0 .. 2*MM_BLOCKS)                  per-block {mn,mx} float2 pairs
//   [.. + nimg*32*NBINS)                partial histograms (unsigned)
//   [.. + nimg)                         thresholds (float)

// ---------------------------------------------------------------------------
// Phase 1: per-block min/max. 4-deep unrolled independent loads (MLP).
// ---------------------------------------------------------------------------
__global__ void __launch_bounds__(BLOCK)
k_minmax(const float4* __restrict__ x, float2* __restrict__ bmm, long n4) {
    float mn = __builtin_inff(), mx = -__builtin_inff();
    const long stride = (long)gridDim.x * BLOCK;
    long i = (long)blockIdx.x * BLOCK + threadIdx.x;
    for (; i + 3 * stride < n4; i += 4 * stride) {
        float4 a = x[i];
        float4 b = x[i + stride];
        float4 c = x[i + 2 * stride];
        float4 d = x[i + 3 * stride];
        mn = fminf(mn, fminf(fminf(a.x, a.y), fminf(a.z, a.w)));
        mx = fmaxf(mx, fmaxf(fmaxf(a.x, a.y), fmaxf(a.z, a.w)));
        mn = fminf(mn, fminf(fminf(b.x, b.y), fminf(b.z, b.w)));
        mx = fmaxf(mx, fmaxf(fmaxf(b.x, b.y), fmaxf(b.z, b.w)));
        mn = fminf(mn, fminf(fminf(c.x, c.y), fminf(c.z, c.w)));
        mx = fmaxf(mx, fmaxf(fmaxf(c.x, c.y), fmaxf(c.z, c.w)));
        mn = fminf(mn, fminf(fminf(d.x, d.y), fminf(d.z, d.w)));
        mx = fmaxf(mx, fmaxf(fmaxf(d.x, d.y), fmaxf(d.z, d.w)));
    }
    for (; i < n4; i += stride) {
        float4 a = x[i];
        mn = fminf(mn, fminf(fminf(a.x, a.y), fminf(a.z, a.w)));
        mx = fmaxf(mx, fmaxf(fmaxf(a.x, a.y), fmaxf(a.z, a.w)));
    }
    for (int off = 32; off; off >>= 1) {
        mn = fminf(mn, __shfl_down(mn, off));
        mx = fmaxf(mx, __shfl_down(mx, off));
    }
    __shared__ float smn[4], smx[4];
    int lane = threadIdx.x & 63, wv = threadIdx.x >> 6;
    if (lane == 0) { smn[wv] = mn; smx[wv] = mx; }
    __syncthreads();
    if (threadIdx.x == 0) {
        for (int j = 1; j < BLOCK / 64; j++) {
            mn = fminf(mn, smn[j]); mx = fmaxf(mx, smx[j]);
        }
        bmm[blockIdx.x] = make_float2(mn, mx);
    }
}

// Redundant deterministic reduce of all MM_BLOCKS pairs, done per-block.
// Identical order in every block -> identical float results everywhere.
__device__ __forceinline__ void reduce_bmm(const float2* __restrict__ bmm,
                                           unsigned* sh_u, float* omn, float* omx) {
    float mn = __builtin_inff(), mx = -__builtin_inff();
    for (int j = threadIdx.x; j < MM_BLOCKS; j += BLOCK) {
        float2 v = bmm[j];
        mn = fminf(mn, v.x); mx = fmaxf(mx, v.y);
    }
    for (int off = 32; off; off >>= 1) {
        mn = fminf(mn, __shfl_down(mn, off));
        mx = fmaxf(mx, __shfl_down(mx, off));
    }
    int lane = threadIdx.x & 63, wv = threadIdx.x >> 6;
    if (lane == 0) { sh_u[2 * wv] = __float_as_uint(mn); sh_u[2 * wv + 1] = __float_as_uint(mx); }
    __syncthreads();
    if (threadIdx.x == 0) {
        for (int j = 1; j < BLOCK / 64; j++) {
            mn = fminf(mn, __uint_as_float(sh_u[2 * j]));
            mx = fmaxf(mx, __uint_as_float(sh_u[2 * j + 1]));
        }
        sh_u[0] = __float_as_uint(mn); sh_u[1] = __float_as_uint(mx);
    }
    __syncthreads();
    *omn = __uint_as_float(sh_u[0]);
    *omx = __uint_as_float(sh_u[1]);
    __syncthreads(); // everyone read sh_u[0..1] before caller reuses the buffer
}

// ---------------------------------------------------------------------------
// Phase 2: per-chunk histograms. 768 blocks x exactly 2 chunks, all resident.
// 32 bank-aligned histogram copies: copy c occupies only bank c; lanes L and
// L+32 share a copy (2 lanes/bank = wave64 minimum, free per m136).
// ---------------------------------------------------------------------------
__global__ void __launch_bounds__(BLOCK)
k_hist(const float4* __restrict__ x, const float2* __restrict__ bmm,
       unsigned* __restrict__ partial, int nimg) {
    __shared__ unsigned sh[NBINS * NCOPY]; // 32 KB
    float mn, mx;
    reduce_bmm(bmm, sh, &mn, &mx);
    float span = mx - mn;                    // fp32 sub, matches np
    float scale = __fdiv_rn(256.0f, span);   // NBINS/span in fp32

    const int nchunks = nimg * CHUNKS_PER_IMG;
    const int tid = threadIdx.x;
    const int c = tid & (NCOPY - 1);
    for (int chunk = blockIdx.x; chunk < nchunks; chunk += HIST_BLOCKS) {
        for (int i = tid; i < NBINS * NCOPY; i += BLOCK) sh[i] = 0u;
        __syncthreads();
        const float4* base = x + ((long)(chunk >> 5) << HW4_SHIFT)
                               + (long)(chunk & (CHUNKS_PER_IMG - 1)) * CHUNK4;
        for (int i = tid; i < CHUNK4; i += 2 * BLOCK) {
            float4 v0 = base[i];
            float4 v1 = base[i + BLOCK];
            // (x - mn) * scale : sub then mul, not an FMA shape -> no contraction
            int b0 = (int)floorf((v0.x - mn) * scale);
            int b1 = (int)floorf((v0.y - mn) * scale);
            int b2 = (int)floorf((v0.z - mn) * scale);
            int b3 = (int)floorf((v0.w - mn) * scale);
            int b4 = (int)floorf((v1.x - mn) * scale);
            int b5 = (int)floorf((v1.y - mn) * scale);
            int b6 = (int)floorf((v1.z - mn) * scale);
            int b7 = (int)floorf((v1.w - mn) * scale);
            b0 = min(max(b0, 0), NBINS - 1); b1 = min(max(b1, 0), NBINS - 1);
            b2 = min(max(b2, 0), NBINS - 1); b3 = min(max(b3, 0), NBINS - 1);
            b4 = min(max(b4, 0), NBINS - 1); b5 = min(max(b5, 0), NBINS - 1);
            b6 = min(max(b6, 0), NBINS - 1); b7 = min(max(b7, 0), NBINS - 1);
            atomicAdd(&sh[b0 * NCOPY + c], 1u);
            atomicAdd(&sh[b1 * NCOPY + c], 1u);
            atomicAdd(&sh[b2 * NCOPY + c], 1u);
            atomicAdd(&sh[b3 * NCOPY + c], 1u);
            atomicAdd(&sh[b4 * NCOPY + c], 1u);
            atomicAdd(&sh[b5 * NCOPY + c], 1u);
            atomicAdd(&sh[b6 * NCOPY + c], 1u);
            atomicAdd(&sh[b7 * NCOPY + c], 1u);
        }
        __syncthreads();
        // BLOCK == NBINS: thread t owns bin t; staggered copy index keeps 2 lanes/bank
        unsigned sum = 0;
        #pragma unroll
        for (int k = 0; k < NCOPY; k++) {
            int cc = (k + tid) & (NCOPY - 1);
            sum += sh[tid * NCOPY + cc];
        }
        partial[(long)chunk * NBINS + tid] = sum; // plain store, no init required
        __syncthreads(); // sum-read done before next iteration re-zeros sh
    }
}

// ---------------------------------------------------------------------------
// Phase 3: Otsu per image. Sequential fp32 cumsum on thread 0 (bit-exact
// np.cumsum order); variance + first-max argmax parallel across 256 threads.
// ---------------------------------------------------------------------------
__global__ void __launch_bounds__(BLOCK)
k_otsu(const unsigned* __restrict__ partial, const float2* __restrict__ bmm,
       float* __restrict__ thresh) {
    __shared__ unsigned sh[3 * NBINS + 8];
    float mn, mx;
    reduce_bmm(bmm, sh, &mn, &mx);

    const int img = blockIdx.x;
    const int tid = threadIdx.x;
    const unsigned* p = partial + (long)img * CHUNKS_PER_IMG * NBINS;
    unsigned hsum = 0;
    #pragma unroll 4
    for (int k = 0; k < CHUNKS_PER_IMG; k++) hsum += p[k * NBINS + tid];
    sh[tid] = hsum;
    __syncthreads();
    if (tid == 0) {
        const float inv_total = 1.0f / 1048576.0f; // exact 2^-20; p exact (counts <= 2^20)
        float ww = 0.0f, ss = 0.0f;
        for (int t = 0; t < NBINS; t++) {
            float pp = __fmul_rn((float)sh[t], inv_total);
            ww = __fadd_rn(ww, pp);
            ss = __fadd_rn(ss, __fmul_rn(pp, (float)t));
            sh[NBINS + t] = __float_as_uint(ww);
            sh[2 * NBINS + t] = __float_as_uint(ss);
        }
    }
    __syncthreads();
    float total = __uint_as_float(sh[3 * NBINS - 1]);
    float ww = __uint_as_float(sh[NBINS + tid]);
    float ss = __uint_as_float(sh[2 * NBINS + tid]);
    float wf = __fsub_rn(1.0f, ww);
    float var;
    if (ww > 0.0f && wf > 0.0f) {
        float mb = __fdiv_rn(ss, ww);
        float mf = __fdiv_rn(__fsub_rn(total, ss), wf);
        float d = __fsub_rn(mb, mf);
        var = __fmul_rn(__fmul_rn(ww, wf), __fmul_rn(d, d));
    } else {
        var = -__builtin_inff();
    }
    // first-max argmax: key = (enc(var) << 32) | (255 - t); max-reduce
    unsigned long long key = ((unsigned long long)enc_f(var) << 32)
                           | (unsigned)(NBINS - 1 - tid);
    for (int off = 32; off; off >>= 1) {
        unsigned long long o = __shfl_down(key, off);
        key = key > o ? key : o;
    }
    int lane = tid & 63, wv = tid >> 6;
    if (lane == 0) {
        sh[3 * NBINS + 2 * wv] = (unsigned)(key & 0xFFFFFFFFull);
        sh[3 * NBINS + 2 * wv + 1] = (unsigned)(key >> 32);
    }
    __syncthreads();
    if (tid == 0) {
        for (int j = 1; j < BLOCK / 64; j++) {
            unsigned long long o = ((unsigned long long)sh[3 * NBINS + 2 * j + 1] << 32)
                                 | sh[3 * NBINS + 2 * j];
            key = key > o ? key : o;
        }
        int bestt = NBINS - 1 - (int)(key & 0xFFFFFFFFull);
        float sp = __fsub_rn(mx, mn);
        float q = __fmul_rn((float)(bestt + 1), 1.0f / 256.0f); // exact (pow2)
        thresh[img] = __fadd_rn(mn, __fmul_rn(sp, q));          // mul then add, no fma
    }
}

// ---------------------------------------------------------------------------
// Phase 4: apply. L3-hit read + NT write, 2-deep unroll, 32 waves/CU.
// ---------------------------------------------------------------------------
__global__ void __launch_bounds__(BLOCK)
k_apply(const float4* __restrict__ x, nfloat4* __restrict__ out,
        const float* __restrict__ thresh, long n4, int nimg) {
    __shared__ unsigned sth[NBINS];
    if (threadIdx.x < nimg) sth[threadIdx.x] = __float_as_uint(thresh[threadIdx.x]);
    __syncthreads();
    const long stride = (long)gridDim.x * BLOCK;
    long i = (long)blockIdx.x * BLOCK + threadIdx.x;
    for (; i + stride < n4; i += 2 * stride) {
        float4 v0 = x[i];
        float4 v1 = x[i + stride];
        float t0 = __uint_as_float(sth[(int)(i >> HW4_SHIFT)]);
        float t1 = __uint_as_float(sth[(int)((i + stride) >> HW4_SHIFT)]);
        nfloat4 o0, o1;
        o0.x = (v0.x <= t0) ? 0.0f : v0.x;
        o0.y = (v0.y <= t0) ? 0.0f : v0.y;
        o0.z = (v0.z <= t0) ? 0.0f : v0.z;
        o0.w = (v0.w <= t0) ? 0.0f : v0.w;
        o1.x = (v1.x <= t1) ? 0.0f : v1.x;
        o1.y = (v1.y <= t1) ? 0.0f : v1.y;
        o1.z = (v1.z <= t1) ? 0.0f : v1.z;
        o1.w = (v1.w <= t1) ? 0.0f : v1.w;
        __builtin_nontemporal_store(o0, &out[i]);          // don't evict x from L3
        __builtin_nontemporal_store(o1, &out[i + stride]);
    }
    for (; i < n4; i += stride) {
        float4 v0 = x[i];
        float t0 = __uint_as_float(sth[(int)(i >> HW4_SHIFT)]);
        nfloat4 o0;
        o0.x = (v0.x <= t0) ? 0.0f : v0.x;
        o0.y = (v0.y <= t0) ? 0.0f : v0.y;
        o0.z = (v0.z <= t0) ? 0.0f : v0.z;
        o0.w = (v0.w <= t0) ? 0.0f : v0.w;
        __builtin_nontemporal_store(o0, &out[i]);
    }
}

extern "C" void kernel_launch(void* const* d_in, const int* in_sizes, int n_in,
                              void* d_out, int out_size, void* d_ws, size_t ws_size,
                              hipStream_t stream) {
    const float4* x = (const float4*)d_in[0];
    nfloat4* out = (nfloat4*)d_out;
    long n = (long)in_sizes[0];          // 48 * 2^20 floats
    long n4 = n >> 2;
    int nimg = (int)(n >> HW_SHIFT);     // 48

    float2* bmm = (float2*)d_ws;
    unsigned* partial = (unsigned*)((float*)d_ws + 2 * MM_BLOCKS);
    float* thresh = (float*)(partial + (long)nimg * CHUNKS_PER_IMG * NBINS);

    k_minmax<<<MM_BLOCKS, BLOCK, 0, stream>>>(x, bmm, n4);
    k_hist<<<HIST_BLOCKS, BLOCK, 0, stream>>>(x, bmm, partial, nimg);
    k_otsu<<<nimg, BLOCK, 0, stream>>>(partial, bmm, thresh);
    k_apply<<<APPLY_BLOCKS, BLOCK, 0, stream>>>(x, out, thresh, n4, nimg);
}